// Round 5
// baseline (32.998 us; speedup 1.0000x reference)
//
#include <hip/hip_runtime.h>
#include <math.h>

constexpr int NT   = 256;   // threads per block
constexpr int DIMV = 256;   // volume D=H=W
constexpr int RS   = 8;     // staged region side (voxels)
constexpr int RROW = 9;     // linear row stride (floats)
constexpr int SROW = 9;     // packed row stride (float4 slots)
constexpr int SSLICE = RS * SROW;   // 72 slots per z-slice

__device__ __forceinline__ float rflf(float x) {
    return __uint_as_float(__builtin_amdgcn_readfirstlane(__float_as_uint(x)));
}
__device__ __forceinline__ float fexp2(float x) {
#if __has_builtin(__builtin_amdgcn_exp2f)
    return __builtin_amdgcn_exp2f(x);
#else
    return __expf(x * 0.6931471805599453f);
#endif
}

// ---------------- pre-pass: per-batch uniform params -> d_ws[B][16] ----------
__global__ __launch_bounds__(256) void psf_prep_kernel(
    const float* __restrict__ sampleGrid,  // [B,3]
    const float* __restrict__ ax,          // [B,6]
    const float* __restrict__ bound,       // [B,2,3]
    const float* __restrict__ invcov,      // [B,3,3]
    float* __restrict__ params,            // [B,16]
    int B)
{
    const int b = blockIdx.x * blockDim.x + threadIdx.x;
    if (b >= B) return;

    const float v0 = ax[b*6+0], v1 = ax[b*6+1], v2 = ax[b*6+2];
    const float t0 = ax[b*6+3], t1 = ax[b*6+4], t2 = ax[b*6+5];
    const float theta = sqrtf(v0*v0 + v1*v1 + v2*v2 + 1e-12f);
    const float inv = 1.0f / theta;
    const float kx = v0*inv, ky = v1*inv, kz = v2*inv;
    const float sn = sinf(theta);
    const float cn = 1.0f - cosf(theta);
    const float R00 = 1.0f - cn*(ky*ky + kz*kz);
    const float R01 = -sn*kz + cn*kx*ky;
    const float R02 =  sn*ky + cn*kx*kz;
    const float R10 =  sn*kz + cn*kx*ky;
    const float R11 = 1.0f - cn*(kx*kx + kz*kz);
    const float R12 = -sn*kx + cn*ky*kz;
    const float R20 = -sn*ky + cn*kx*kz;
    const float R21 =  sn*kx + cn*ky*kz;
    const float R22 = 1.0f - cn*(kx*kx + ky*ky);
    const float g0 = sampleGrid[b*3+0] + t0;
    const float g1 = sampleGrid[b*3+1] + t1;
    const float g2 = sampleGrid[b*3+2] + t2;
    const float ms0 = R00*g0 + R01*g1 + R02*g2;
    const float ms1 = R10*g0 + R11*g1 + R12*g2;
    const float ms2 = R20*g0 + R21*g1 + R22*g2;
    const float h0 = (bound[b*6+3] - bound[b*6+0]) * 0.5f;
    const float h1 = (bound[b*6+4] - bound[b*6+1]) * 0.5f;
    const float h2 = (bound[b*6+5] - bound[b*6+2]) * 0.5f;
    const float M00 = invcov[b*9+0], M01 = invcov[b*9+1], M02 = invcov[b*9+2];
    const float M11 = invcov[b*9+4], M12 = invcov[b*9+5], M22 = invcov[b*9+8];

    const float LOG2E = 1.4426950408889634f;
    const float kk = 256.0f / 255.0f;
    const float cix = fmaf(ms0, kk, -0.5f);
    const float ciy = fmaf(ms1, kk, -0.5f);
    const float ciz = fmaf(ms2, kk, -0.5f);
    const float hx = h0 * kk, hy = h1 * kk, hz = h2 * kk;
    const int bx = (int)floorf(cix - hx - 1e-3f);
    const int by = (int)floorf(ciy - hy - 1e-3f);
    const int bz = (int)floorf(ciz - hz - 1e-3f);
    const bool fast = (hx <= 2.9f) && (hy <= 2.9f) && (hz <= 2.9f);

    float4* p = reinterpret_cast<float4*>(params + (size_t)b * 16);
    p[0] = make_float4(cix, ciy, ciz, hx);
    p[1] = make_float4(hy, hz,
                       -0.5f * M00 * h0 * h0 * LOG2E,
                       -0.5f * M11 * h1 * h1 * LOG2E);
    p[2] = make_float4(-0.5f * M22 * h2 * h2 * LOG2E,
                       -M01 * h0 * h1 * LOG2E,
                       -M02 * h0 * h2 * LOG2E,
                       -M12 * h1 * h2 * LOG2E);
    p[3] = make_float4((float)bx, (float)by, (float)bz, fast ? 1.0f : 0.0f);
}

// ---------------- main kernel ----------------
__global__ __launch_bounds__(NT, 6) void psf_sample_kernel(
    const float* __restrict__ vol,     // [256^3]
    const float* __restrict__ params,  // [B,16]
    const float* __restrict__ xyz,     // [B,n,3]
    float* __restrict__ out,           // [B]
    int n)
{
    const int b   = blockIdx.x;
    const int tid = threadIdx.x;

    __shared__ float  s_lin[RS * RS * RROW];        // 576 floats, linear stage
    __shared__ float4 s_q[(RS*RS - 1) * SROW + RS]; // 575 slots, quad-packed
    __shared__ float  s_red[2 * (NT / 64)];

    const float4* pp = reinterpret_cast<const float4*>(params + (size_t)b * 16);
    const float4 P0 = pp[0];
    const float4 P1 = pp[1];
    const float4 P2 = pp[2];
    const float4 P3 = pp[3];

    const float cix = rflf(P0.x), ciy = rflf(P0.y), ciz = rflf(P0.z);
    const float hx  = rflf(P0.w), hy  = rflf(P1.x), hz  = rflf(P1.y);
    const float Bxx = rflf(P1.z), Byy = rflf(P1.w), Bzz = rflf(P2.x);
    const float Bxy = rflf(P2.y), Bxz = rflf(P2.z), Byz = rflf(P2.w);
    const int bx = __builtin_amdgcn_readfirstlane((int)P3.x);
    const int by = __builtin_amdgcn_readfirstlane((int)P3.y);
    const int bz = __builtin_amdgcn_readfirstlane((int)P3.z);
    const bool fast = P3.w > 0.5f;
    const float addrC = rflf((float)(bz * SSLICE + by * SROW + bx));
    const float LOG2E = 1.4426950408889634f;

    // ---- stage 8^3 region (linear) ----
    if (fast) {
        #pragma unroll
        for (int pass = 0; pass < (RS*RS*RS)/NT; ++pass) {
            const int idx = pass * NT + tid;
            const int lx = idx & 7, ly = (idx >> 3) & 7, lz = idx >> 6;
            const int gx = bx + lx, gy = by + ly, gz = bz + lz;
            float v = 0.0f;
            if ((unsigned)gx < (unsigned)DIMV && (unsigned)gy < (unsigned)DIMV &&
                (unsigned)gz < (unsigned)DIMV)
                v = vol[((size_t)gz * DIMV + gy) * DIMV + gx];
            s_lin[(lz * RS + ly) * RROW + lx] = v;
        }
        __syncthreads();
        // ---- repack to 2x2 xy-quads (float4 per slot) ----
        #pragma unroll
        for (int pass = 0; pass < (RS*RS*RS)/NT; ++pass) {
            const int idx = pass * NT + tid;
            const int lx = idx & 7, ly = (idx >> 3) & 7, lz = idx >> 6;
            const int x1 = lx < 7 ? lx + 1 : 7;   // lx==7 slot never read
            const int y1 = ly < 7 ? ly + 1 : 7;   // ly==7 slot never read
            const int r0 = (lz * RS + ly) * RROW;
            const int r1 = (lz * RS + y1) * RROW;
            s_q[(lz * RS + ly) * SROW + lx] =
                make_float4(s_lin[r0 + lx], s_lin[r0 + x1],
                            s_lin[r1 + lx], s_lin[r1 + x1]);
        }
    }
    __syncthreads();

    float sum_wx = 0.0f, sum_w = 0.0f;

    auto doSample = [&](float rx, float ry, float rz) {
        const float ex = fexp2(rx * -LOG2E);
        const float ey = fexp2(ry * -LOG2E);
        const float ez = fexp2(rz * -LOG2E);
        const float sx = (1.0f - ex) * __builtin_amdgcn_rcpf(1.0f + ex);
        const float sy = (1.0f - ey) * __builtin_amdgcn_rcpf(1.0f + ey);
        const float sz = (1.0f - ez) * __builtin_amdgcn_rcpf(1.0f + ez);

        const float ixf = fmaf(sx, hx, cix);
        const float iyf = fmaf(sy, hy, ciy);
        const float izf = fmaf(sz, hz, ciz);
        const float x0f = floorf(ixf), y0f = floorf(iyf), z0f = floorf(izf);
        const float fx = ixf - x0f, fy = iyf - y0f, fz = izf - z0f;

        float val;
        if (fast) {
            // float-domain slot index (exact small integers)
            const float ef = fmaf(z0f, (float)SSLICE,
                             fmaf(y0f, (float)SROW, x0f - addrC));
            const int e = (int)ef;
            const float4 q0 = s_q[e];            // z0 slice: 2x2 xy-quad
            const float4 q1 = s_q[e + SSLICE];   // z1 slice
            const float a00 = fmaf(fx, q0.y - q0.x, q0.x);
            const float a01 = fmaf(fx, q0.w - q0.z, q0.z);
            const float a0  = fmaf(fy, a01 - a00, a00);
            const float a10 = fmaf(fx, q1.y - q1.x, q1.x);
            const float a11 = fmaf(fx, q1.w - q1.z, q1.z);
            const float a1  = fmaf(fy, a11 - a10, a10);
            val = fmaf(fz, a1 - a0, a0);
        } else {
            const int x0 = (int)x0f, y0 = (int)y0f, z0 = (int)z0f;
            const int x1 = x0 + 1, y1 = y0 + 1, z1 = z0 + 1;
            const bool vx0 = (unsigned)x0 < (unsigned)DIMV;
            const bool vx1 = (unsigned)x1 < (unsigned)DIMV;
            const bool vy0 = (unsigned)y0 < (unsigned)DIMV;
            const bool vy1 = (unsigned)y1 < (unsigned)DIMV;
            const bool vz0 = (unsigned)z0 < (unsigned)DIMV;
            const bool vz1 = (unsigned)z1 < (unsigned)DIMV;
            const int cx0 = min(max(x0,0),DIMV-1), cx1 = min(max(x1,0),DIMV-1);
            const int cy0 = min(max(y0,0),DIMV-1), cy1 = min(max(y1,0),DIMV-1);
            const int cz0 = min(max(z0,0),DIMV-1), cz1 = min(max(z1,0),DIMV-1);
            const float wx0 = 1.0f-fx, wx1 = fx, wy0 = 1.0f-fy, wy1 = fy;
            const float wz0 = 1.0f-fz, wz1 = fz;
            const int r00 = (cz0*DIMV + cy0)*DIMV, r01 = (cz0*DIMV + cy1)*DIMV;
            const int r10 = (cz1*DIMV + cy0)*DIMV, r11 = (cz1*DIMV + cy1)*DIMV;
            val  = (vz0&&vy0&&vx0) ? vol[r00+cx0]*(wz0*wy0*wx0) : 0.0f;
            val += (vz0&&vy0&&vx1) ? vol[r00+cx1]*(wz0*wy0*wx1) : 0.0f;
            val += (vz0&&vy1&&vx0) ? vol[r01+cx0]*(wz0*wy1*wx0) : 0.0f;
            val += (vz0&&vy1&&vx1) ? vol[r01+cx1]*(wz0*wy1*wx1) : 0.0f;
            val += (vz1&&vy0&&vx0) ? vol[r10+cx0]*(wz1*wy0*wx0) : 0.0f;
            val += (vz1&&vy0&&vx1) ? vol[r10+cx1]*(wz1*wy0*wx1) : 0.0f;
            val += (vz1&&vy1&&vx0) ? vol[r11+cx0]*(wz1*wy1*wx0) : 0.0f;
            val += (vz1&&vy1&&vx1) ? vol[r11+cx1]*(wz1*wy1*wx1) : 0.0f;
        }

        const float f = fmaf(Bxx, sx*sx,
                        fmaf(Byy, sy*sy,
                        fmaf(Bzz, sz*sz,
                        fmaf(Bxy, sx*sy,
                        fmaf(Bxz, sx*sz, Byz * (sy*sz))))));
        const float w = fexp2(f);
        sum_w  += w;
        sum_wx = fmaf(w, val, sum_wx);
    };

    // 4 samples per iteration via 3 coalesced float4 loads
    const int ng = n >> 2;
    const float4* __restrict__ xb4 =
        reinterpret_cast<const float4*>(xyz + (size_t)b * n * 3);
    for (int g = tid; g < ng; g += NT) {
        const float4 q0 = xb4[g*3 + 0];
        const float4 q1 = xb4[g*3 + 1];
        const float4 q2 = xb4[g*3 + 2];
        doSample(q0.x, q0.y, q0.z);
        doSample(q0.w, q1.x, q1.y);
        doSample(q1.z, q1.w, q2.x);
        doSample(q2.y, q2.z, q2.w);
    }
    // generic tail (unused when n % 4 == 0)
    const float* __restrict__ xb = xyz + (size_t)b * n * 3;
    for (int i = (ng << 2) + tid; i < n; i += NT)
        doSample(xb[i*3+0], xb[i*3+1], xb[i*3+2]);

    // wave64 reduction
    #pragma unroll
    for (int off = 32; off > 0; off >>= 1) {
        sum_wx += __shfl_down(sum_wx, off);
        sum_w  += __shfl_down(sum_w,  off);
    }
    const int wave = tid >> 6;
    const int lane = tid & 63;
    if (lane == 0) { s_red[wave*2] = sum_wx; s_red[wave*2+1] = sum_w; }
    __syncthreads();
    if (tid == 0) {
        float twx = 0.0f, tw = 0.0f;
        #pragma unroll
        for (int wv = 0; wv < NT/64; ++wv) { twx += s_red[wv*2]; tw += s_red[wv*2+1]; }
        out[b] = twx / tw;
    }
}

extern "C" void kernel_launch(void* const* d_in, const int* in_sizes, int n_in,
                              void* d_out, int out_size, void* d_ws, size_t ws_size,
                              hipStream_t stream) {
    const float* vol        = (const float*)d_in[0];
    const float* sampleGrid = (const float*)d_in[1];
    const float* ax         = (const float*)d_in[2];
    const float* bound      = (const float*)d_in[3];
    const float* invcov     = (const float*)d_in[4];
    // d_in[5] = psf_sigma (unused by reference)
    const float* xyz        = (const float*)d_in[6];
    float* out              = (float*)d_out;
    float* params           = (float*)d_ws;   // [B,16] floats = 256 KB

    const int B = in_sizes[1] / 3;
    const int n = in_sizes[6] / (B * 3);

    psf_prep_kernel<<<(B + 255) / 256, 256, 0, stream>>>(sampleGrid, ax, bound,
                                                         invcov, params, B);
    psf_sample_kernel<<<B, NT, 0, stream>>>(vol, params, xyz, out, n);
}

// Round 6
// 29.150 us; speedup vs baseline: 1.1320x; 1.1320x over previous
//
#include <hip/hip_runtime.h>
#include <math.h>

constexpr int NT   = 256;   // threads per block (4 waves)
constexpr int WPB  = 4;     // waves per block = batches per block
constexpr int DIMV = 256;   // volume D=H=W
constexpr int RS   = 8;     // staged region side (voxels)
constexpr int RROW = 9;     // padded row stride (floats)
constexpr int RSLICE = RS * RROW;  // 72

__device__ __forceinline__ float rflf(float x) {
    return __uint_as_float(__builtin_amdgcn_readfirstlane(__float_as_uint(x)));
}
__device__ __forceinline__ float fexp2(float x) {
#if __has_builtin(__builtin_amdgcn_exp2f)
    return __builtin_amdgcn_exp2f(x);
#else
    return __expf(x * 0.6931471805599453f);
#endif
}

__global__ __launch_bounds__(NT, 4) void psf_sample_kernel(
    const float* __restrict__ vol,         // [256^3]
    const float* __restrict__ sampleGrid,  // [B,3]
    const float* __restrict__ ax,          // [B,6]
    const float* __restrict__ bound,       // [B,2,3]
    const float* __restrict__ invcov,      // [B,3,3] (symmetric)
    const float* __restrict__ xyz,         // [B,n,3]
    float* __restrict__ out,               // [B]
    int n, int B)
{
    const int tid  = threadIdx.x;
    const int wid  = tid >> 6;
    const int lane = tid & 63;
    const int b    = blockIdx.x * WPB + wid;
    const bool valid = b < B;

    __shared__ float s_vol[WPB][RS * RSLICE];   // 4 x 576 floats = 9216 B

    const float LOG2E = 1.4426950408889634f;
    float cix, ciy, ciz, hx, hy, hz, addrC;
    float Bxx, Byy, Bzz, Bxy, Bxz, Byz;
    int bx = 0, by = 0, bz = 0;
    bool fast = false;
    float h0 = 0, h1 = 0, h2 = 0;

    if (valid) {
        // ---- per-batch params (wave-uniform; redundant across lanes, SGPR-ified) ----
        const float v0 = ax[b*6+0], v1 = ax[b*6+1], v2 = ax[b*6+2];
        const float t0 = ax[b*6+3], t1 = ax[b*6+4], t2 = ax[b*6+5];
        const float theta = sqrtf(v0*v0 + v1*v1 + v2*v2 + 1e-12f);
        const float inv = 1.0f / theta;
        const float kx = v0*inv, ky = v1*inv, kz = v2*inv;
        const float sn = sinf(theta);
        const float cn = 1.0f - cosf(theta);
        const float R00 = 1.0f - cn*(ky*ky + kz*kz);
        const float R01 = -sn*kz + cn*kx*ky;
        const float R02 =  sn*ky + cn*kx*kz;
        const float R10 =  sn*kz + cn*kx*ky;
        const float R11 = 1.0f - cn*(kx*kx + kz*kz);
        const float R12 = -sn*kx + cn*ky*kz;
        const float R20 = -sn*ky + cn*kx*kz;
        const float R21 =  sn*kx + cn*ky*kz;
        const float R22 = 1.0f - cn*(kx*kx + ky*ky);
        const float g0 = sampleGrid[b*3+0] + t0;
        const float g1 = sampleGrid[b*3+1] + t1;
        const float g2 = sampleGrid[b*3+2] + t2;
        const float ms0 = R00*g0 + R01*g1 + R02*g2;
        const float ms1 = R10*g0 + R11*g1 + R12*g2;
        const float ms2 = R20*g0 + R21*g1 + R22*g2;
        h0 = (bound[b*6+3] - bound[b*6+0]) * 0.5f;
        h1 = (bound[b*6+4] - bound[b*6+1]) * 0.5f;
        h2 = (bound[b*6+5] - bound[b*6+2]) * 0.5f;
        const float M00 = invcov[b*9+0], M01 = invcov[b*9+1], M02 = invcov[b*9+2];
        const float M11 = invcov[b*9+4], M12 = invcov[b*9+5], M22 = invcov[b*9+8];

        Bxx = rflf(-0.5f * M00 * h0 * h0 * LOG2E);
        Byy = rflf(-0.5f * M11 * h1 * h1 * LOG2E);
        Bzz = rflf(-0.5f * M22 * h2 * h2 * LOG2E);
        Bxy = rflf(-M01 * h0 * h1 * LOG2E);
        Bxz = rflf(-M02 * h0 * h2 * LOG2E);
        Byz = rflf(-M12 * h1 * h2 * LOG2E);

        const float kk = 256.0f / 255.0f;
        cix = rflf(fmaf(ms0, kk, -0.5f));
        ciy = rflf(fmaf(ms1, kk, -0.5f));
        ciz = rflf(fmaf(ms2, kk, -0.5f));
        hx  = rflf(h0 * kk);
        hy  = rflf(h1 * kk);
        hz  = rflf(h2 * kk);

        bx = __builtin_amdgcn_readfirstlane((int)floorf(cix - hx - 1e-3f));
        by = __builtin_amdgcn_readfirstlane((int)floorf(ciy - hy - 1e-3f));
        bz = __builtin_amdgcn_readfirstlane((int)floorf(ciz - hz - 1e-3f));
        addrC = rflf((float)(bz * RSLICE + by * RROW + bx));
        // span fits RS-1 iff 2h*kk + 1.001 < 7 (h <= 2.51 by construction)
        fast = (hx <= 2.9f) && (hy <= 2.9f) && (hz <= 2.9f);

        if (fast) {
            // wave stages its own 8^3 region: 512 floats, 8 per lane
            #pragma unroll
            for (int pass = 0; pass < (RS*RS*RS)/64; ++pass) {
                const int idx = pass * 64 + lane;
                const int lx = idx & 7, ly = (idx >> 3) & 7, lz = idx >> 6;
                const int gx = bx + lx, gy = by + ly, gz = bz + lz;
                float v = 0.0f;
                if ((unsigned)gx < (unsigned)DIMV && (unsigned)gy < (unsigned)DIMV &&
                    (unsigned)gz < (unsigned)DIMV)
                    v = vol[((size_t)gz * DIMV + gy) * DIMV + gx];
                s_vol[wid][(lz * RS + ly) * RROW + lx] = v;
            }
        }
    }
    __syncthreads();   // single barrier; makes each wave's staged LDS visible to itself

    if (valid) {
        float sum_wx = 0.0f, sum_w = 0.0f;
        const float* __restrict__ sreg = s_vol[wid];

        auto doSample = [&](float rx, float ry, float rz) {
            const float ex = fexp2(rx * -LOG2E);
            const float ey = fexp2(ry * -LOG2E);
            const float ez = fexp2(rz * -LOG2E);
            const float sx = (1.0f - ex) * __builtin_amdgcn_rcpf(1.0f + ex);
            const float sy = (1.0f - ey) * __builtin_amdgcn_rcpf(1.0f + ey);
            const float sz = (1.0f - ez) * __builtin_amdgcn_rcpf(1.0f + ez);

            const float ixf = fmaf(sx, hx, cix);
            const float iyf = fmaf(sy, hy, ciy);
            const float izf = fmaf(sz, hz, ciz);
            const float x0f = floorf(ixf), y0f = floorf(iyf), z0f = floorf(izf);
            const float fx = ixf - x0f, fy = iyf - y0f, fz = izf - z0f;

            float val;
            if (fast) {
                const float ef = fmaf(z0f, (float)RSLICE,
                                 fmaf(y0f, (float)RROW, x0f - addrC));
                const int e = (int)ef;
                const float* p = &sreg[e];
                const float v000 = p[0],              v001 = p[1];
                const float v010 = p[RROW],           v011 = p[RROW + 1];
                const float v100 = p[RSLICE],         v101 = p[RSLICE + 1];
                const float v110 = p[RSLICE + RROW],  v111 = p[RSLICE + RROW + 1];
                const float a00 = fmaf(fx, v001 - v000, v000);
                const float a01 = fmaf(fx, v011 - v010, v010);
                const float a10 = fmaf(fx, v101 - v100, v100);
                const float a11 = fmaf(fx, v111 - v110, v110);
                const float a0  = fmaf(fy, a01 - a00, a00);
                const float a1  = fmaf(fy, a11 - a10, a10);
                val = fmaf(fz, a1 - a0, a0);
            } else {
                const int x0 = (int)x0f, y0 = (int)y0f, z0 = (int)z0f;
                const int x1 = x0 + 1, y1 = y0 + 1, z1 = z0 + 1;
                const bool vx0 = (unsigned)x0 < (unsigned)DIMV;
                const bool vx1 = (unsigned)x1 < (unsigned)DIMV;
                const bool vy0 = (unsigned)y0 < (unsigned)DIMV;
                const bool vy1 = (unsigned)y1 < (unsigned)DIMV;
                const bool vz0 = (unsigned)z0 < (unsigned)DIMV;
                const bool vz1 = (unsigned)z1 < (unsigned)DIMV;
                const int cx0 = min(max(x0,0),DIMV-1), cx1 = min(max(x1,0),DIMV-1);
                const int cy0 = min(max(y0,0),DIMV-1), cy1 = min(max(y1,0),DIMV-1);
                const int cz0 = min(max(z0,0),DIMV-1), cz1 = min(max(z1,0),DIMV-1);
                const float wx0 = 1.0f-fx, wx1 = fx, wy0 = 1.0f-fy, wy1 = fy;
                const float wz0 = 1.0f-fz, wz1 = fz;
                const int r00 = (cz0*DIMV + cy0)*DIMV, r01 = (cz0*DIMV + cy1)*DIMV;
                const int r10 = (cz1*DIMV + cy0)*DIMV, r11 = (cz1*DIMV + cy1)*DIMV;
                val  = (vz0&&vy0&&vx0) ? vol[r00+cx0]*(wz0*wy0*wx0) : 0.0f;
                val += (vz0&&vy0&&vx1) ? vol[r00+cx1]*(wz0*wy0*wx1) : 0.0f;
                val += (vz0&&vy1&&vx0) ? vol[r01+cx0]*(wz0*wy1*wx0) : 0.0f;
                val += (vz0&&vy1&&vx1) ? vol[r01+cx1]*(wz0*wy1*wx1) : 0.0f;
                val += (vz1&&vy0&&vx0) ? vol[r10+cx0]*(wz1*wy0*wx0) : 0.0f;
                val += (vz1&&vy0&&vx1) ? vol[r10+cx1]*(wz1*wy0*wx1) : 0.0f;
                val += (vz1&&vy1&&vx0) ? vol[r11+cx0]*(wz1*wy1*wx0) : 0.0f;
                val += (vz1&&vy1&&vx1) ? vol[r11+cx1]*(wz1*wy1*wx1) : 0.0f;
            }

            const float f = fmaf(Bxx, sx*sx,
                            fmaf(Byy, sy*sy,
                            fmaf(Bzz, sz*sz,
                            fmaf(Bxy, sx*sy,
                            fmaf(Bxz, sx*sz, Byz * (sy*sz))))));
            const float w = fexp2(f);
            sum_w  += w;
            sum_wx = fmaf(w, val, sum_wx);
        };

        // 32 samples/lane: 8 groups of 4 via 3 coalesced float4 loads each
        const int ng = n >> 2;
        const float4* __restrict__ xb4 =
            reinterpret_cast<const float4*>(xyz + (size_t)b * n * 3);
        for (int g = lane; g < ng; g += 64) {
            const float4 q0 = xb4[g*3 + 0];
            const float4 q1 = xb4[g*3 + 1];
            const float4 q2 = xb4[g*3 + 2];
            doSample(q0.x, q0.y, q0.z);
            doSample(q0.w, q1.x, q1.y);
            doSample(q1.z, q1.w, q2.x);
            doSample(q2.y, q2.z, q2.w);
        }
        // generic tail (unused when n % 4 == 0)
        const float* __restrict__ xb = xyz + (size_t)b * n * 3;
        for (int i = (ng << 2) + lane; i < n; i += 64)
            doSample(xb[i*3+0], xb[i*3+1], xb[i*3+2]);

        // wave64 reduction; lane 0 writes the batch's output
        #pragma unroll
        for (int off = 32; off > 0; off >>= 1) {
            sum_wx += __shfl_down(sum_wx, off);
            sum_w  += __shfl_down(sum_w,  off);
        }
        if (lane == 0) out[b] = sum_wx / sum_w;
    }
}

extern "C" void kernel_launch(void* const* d_in, const int* in_sizes, int n_in,
                              void* d_out, int out_size, void* d_ws, size_t ws_size,
                              hipStream_t stream) {
    const float* vol        = (const float*)d_in[0];
    const float* sampleGrid = (const float*)d_in[1];
    const float* ax         = (const float*)d_in[2];
    const float* bound      = (const float*)d_in[3];
    const float* invcov     = (const float*)d_in[4];
    // d_in[5] = psf_sigma (unused by reference)
    const float* xyz        = (const float*)d_in[6];
    float* out              = (float*)d_out;

    const int B = in_sizes[1] / 3;
    const int n = in_sizes[6] / (B * 3);

    const int grid = (B + WPB - 1) / WPB;
    psf_sample_kernel<<<grid, NT, 0, stream>>>(vol, sampleGrid, ax, bound,
                                               invcov, xyz, out, n, B);
}